// Round 1
// baseline (456.455 us; speedup 1.0000x reference)
//
#include <hip/hip_runtime.h>
#include <math.h>

#define NBINS 4

// bin edges: log1p([0,5,25,50,100]) in float32
// B0 = 0, B1 = log(6), B2 = log(26), B3 = log(51), B4 = log(101)

__global__ __launch_bounds__(256) void qrmse_bins(
    const float4* __restrict__ yp4, const float4* __restrict__ yt4,
    const float* __restrict__ yp, const float* __restrict__ yt,
    float* __restrict__ g_ss, unsigned int* __restrict__ g_cnt,
    int n4, int n)
{
    const float B1 = (float)1.791759469228055;   // log1p(5)
    const float B2 = (float)3.2580965380214821;  // log1p(25)
    const float B3 = (float)3.9318256327243257;  // log1p(50)
    const float B4 = (float)4.6151205168412597;  // log1p(100)

    float ss0 = 0.f, ss1 = 0.f, ss2 = 0.f, ss3 = 0.f;
    unsigned int c0 = 0, c1 = 0, c2 = 0, c3 = 0;

    const int stride = gridDim.x * blockDim.x;
    int tid = blockIdx.x * blockDim.x + threadIdx.x;

    for (int i = tid; i < n4; i += stride) {
        float4 p = yp4[i];
        float4 t = yt4[i];
#define ACC(PC, TC)                                          \
        {                                                    \
            float d  = (PC) - (TC);                          \
            float sq = d * d;                                \
            float tv = (TC);                                 \
            bool b0 = (tv >= 0.f) & (tv < B1);               \
            bool b1 = (tv >= B1)  & (tv < B2);               \
            bool b2 = (tv >= B2)  & (tv < B3);               \
            bool b3 = (tv >= B3)  & (tv < B4);               \
            ss0 += b0 ? sq : 0.f;  c0 += b0;                 \
            ss1 += b1 ? sq : 0.f;  c1 += b1;                 \
            ss2 += b2 ? sq : 0.f;  c2 += b2;                 \
            ss3 += b3 ? sq : 0.f;  c3 += b3;                 \
        }
        ACC(p.x, t.x); ACC(p.y, t.y); ACC(p.z, t.z); ACC(p.w, t.w);
    }

    // scalar tail (N % 4 elements), handled by global thread 0 only
    if (tid == 0) {
        for (int i = n4 * 4; i < n; ++i) {
            float p = yp[i];
            float t = yt[i];
            ACC(p, t);
        }
    }
#undef ACC

    // wave-64 reduction
    for (int off = 32; off > 0; off >>= 1) {
        ss0 += __shfl_down(ss0, off);
        ss1 += __shfl_down(ss1, off);
        ss2 += __shfl_down(ss2, off);
        ss3 += __shfl_down(ss3, off);
        c0  += __shfl_down(c0,  off);
        c1  += __shfl_down(c1,  off);
        c2  += __shfl_down(c2,  off);
        c3  += __shfl_down(c3,  off);
    }

    __shared__ float        s_ss[4][NBINS];  // [wave][bin]
    __shared__ unsigned int s_cnt[4][NBINS];
    const int lane = threadIdx.x & 63;
    const int wave = threadIdx.x >> 6;
    if (lane == 0) {
        s_ss[wave][0] = ss0; s_ss[wave][1] = ss1;
        s_ss[wave][2] = ss2; s_ss[wave][3] = ss3;
        s_cnt[wave][0] = c0; s_cnt[wave][1] = c1;
        s_cnt[wave][2] = c2; s_cnt[wave][3] = c3;
    }
    __syncthreads();

    if (threadIdx.x == 0) {
        float bs[NBINS];
        unsigned int bc[NBINS];
#pragma unroll
        for (int b = 0; b < NBINS; ++b) {
            bs[b] = s_ss[0][b] + s_ss[1][b] + s_ss[2][b] + s_ss[3][b];
            bc[b] = s_cnt[0][b] + s_cnt[1][b] + s_cnt[2][b] + s_cnt[3][b];
        }
#pragma unroll
        for (int b = 0; b < NBINS; ++b) {
            atomicAdd(&g_ss[b], bs[b]);
            atomicAdd(&g_cnt[b], bc[b]);
        }
    }
}

__global__ void qrmse_final(const float* __restrict__ g_ss,
                            const unsigned int* __restrict__ g_cnt,
                            float* __restrict__ out)
{
    if (threadIdx.x == 0 && blockIdx.x == 0) {
        float mse[NBINS], w[NBINS];
        float wsum = 0.f;
        bool any = false;
#pragma unroll
        for (int b = 0; b < NBINS; ++b) {
            unsigned int c = g_cnt[b];
            bool present = (c > 0);
            any |= present;
            float csafe = present ? (float)c : 1.0f;
            mse[b] = g_ss[b] / csafe;
            w[b] = present ? (1.0f / csafe) : 0.0f;
            wsum += w[b];
        }
        float denom = (wsum > 0.f) ? wsum : 1.0f;
        float wmse = 0.f;
#pragma unroll
        for (int b = 0; b < NBINS; ++b) {
            wmse += (w[b] / denom) * mse[b];
        }
        float loss = sqrtf(wmse + 1e-8f);
        out[0] = any ? loss : 0.0f;
    }
}

extern "C" void kernel_launch(void* const* d_in, const int* in_sizes, int n_in,
                              void* d_out, int out_size, void* d_ws, size_t ws_size,
                              hipStream_t stream) {
    const float* yp = (const float*)d_in[0];
    const float* yt = (const float*)d_in[1];
    float* out = (float*)d_out;

    float* g_ss = (float*)d_ws;                       // 4 floats
    unsigned int* g_cnt = (unsigned int*)d_ws + 4;    // 4 uints

    int n = in_sizes[0];
    int n4 = n / 4;

    // zero the accumulators (d_ws is poisoned to 0xAA before every launch)
    hipMemsetAsync(d_ws, 0, 8 * sizeof(float), stream);

    const int block = 256;
    const int grid = 2048;  // 256 CUs * 8 blocks — grid-stride covers the rest
    qrmse_bins<<<grid, block, 0, stream>>>(
        (const float4*)yp, (const float4*)yt, yp, yt, g_ss, g_cnt, n4, n);
    qrmse_final<<<1, 64, 0, stream>>>(g_ss, g_cnt, out);
}

// Round 2
// 291.154 us; speedup vs baseline: 1.5677x; 1.5677x over previous
//
#include <hip/hip_runtime.h>
#include <math.h>

#define NBINS 4
#define SLOTS 64           // atomic-spread slots per bin
#define UNROLL 4           // float4s per thread per input

// ws layout: float ss[NBINS][SLOTS], then uint cnt[NBINS][SLOTS]
// bin edges: log1p([0,5,25,50,100]) in float32

__global__ __launch_bounds__(256) void qrmse_bins(
    const float4* __restrict__ yp4, const float4* __restrict__ yt4,
    const float* __restrict__ yp, const float* __restrict__ yt,
    float* __restrict__ g_ss, unsigned int* __restrict__ g_cnt,
    int n4, int n)
{
    const float B1 = 1.7917594909667969f;   // log1p(5)  rounded to f32
    const float B2 = 3.2580965518951416f;   // log1p(25)
    const float B3 = 3.9318256378173828f;   // log1p(50)
    const float B4 = 4.6151204109191895f;   // log1p(100)

    float ss0 = 0.f, ss1 = 0.f, ss2 = 0.f, ss3 = 0.f;
    unsigned int c0 = 0, c1 = 0, c2 = 0, c3 = 0;

    // flat tiling: block covers UNROLL*blockDim consecutive float4s,
    // lane-contiguous within each of the UNROLL sub-loads (coalesced).
    const int base = blockIdx.x * (blockDim.x * UNROLL) + threadIdx.x;

    float4 p[UNROLL], t[UNROLL];
#pragma unroll
    for (int k = 0; k < UNROLL; ++k) {
        int idx = base + k * 256;
        if (idx < n4) {
            p[k] = yp4[idx];          // 8 independent 16B loads in flight
            t[k] = yt4[idx];
        } else {
            p[k] = make_float4(0.f, 0.f, 0.f, 0.f);
            t[k] = make_float4(-1.f, -1.f, -1.f, -1.f);  // t<0 -> no bin
        }
    }

#define ACC(PC, TC)                                          \
    {                                                        \
        float d  = (PC) - (TC);                              \
        float sq = d * d;                                    \
        float tv = (TC);                                     \
        bool b0 = (tv >= 0.f) & (tv < B1);                   \
        bool b1 = (tv >= B1)  & (tv < B2);                   \
        bool b2 = (tv >= B2)  & (tv < B3);                   \
        bool b3 = (tv >= B3)  & (tv < B4);                   \
        ss0 += b0 ? sq : 0.f;  c0 += b0;                     \
        ss1 += b1 ? sq : 0.f;  c1 += b1;                     \
        ss2 += b2 ? sq : 0.f;  c2 += b2;                     \
        ss3 += b3 ? sq : 0.f;  c3 += b3;                     \
    }

#pragma unroll
    for (int k = 0; k < UNROLL; ++k) {
        ACC(p[k].x, t[k].x); ACC(p[k].y, t[k].y);
        ACC(p[k].z, t[k].z); ACC(p[k].w, t[k].w);
    }

    // scalar tail (n % 4 elements), global thread 0 only (empty for this N)
    if (blockIdx.x == 0 && threadIdx.x == 0) {
        for (int i = n4 * 4; i < n; ++i) {
            float pp = yp[i];
            float tt = yt[i];
            ACC(pp, tt);
        }
    }
#undef ACC

    // wave-64 shuffle reduction
    for (int off = 32; off > 0; off >>= 1) {
        ss0 += __shfl_down(ss0, off);
        ss1 += __shfl_down(ss1, off);
        ss2 += __shfl_down(ss2, off);
        ss3 += __shfl_down(ss3, off);
        c0  += __shfl_down(c0,  off);
        c1  += __shfl_down(c1,  off);
        c2  += __shfl_down(c2,  off);
        c3  += __shfl_down(c3,  off);
    }

    __shared__ float        s_ss[4][NBINS];
    __shared__ unsigned int s_cnt[4][NBINS];
    const int lane = threadIdx.x & 63;
    const int wave = threadIdx.x >> 6;
    if (lane == 0) {
        s_ss[wave][0] = ss0; s_ss[wave][1] = ss1;
        s_ss[wave][2] = ss2; s_ss[wave][3] = ss3;
        s_cnt[wave][0] = c0; s_cnt[wave][1] = c1;
        s_cnt[wave][2] = c2; s_cnt[wave][3] = c3;
    }
    __syncthreads();

    if (threadIdx.x == 0) {
        const int slot = blockIdx.x & (SLOTS - 1);
#pragma unroll
        for (int b = 0; b < NBINS; ++b) {
            float bs = s_ss[0][b] + s_ss[1][b] + s_ss[2][b] + s_ss[3][b];
            unsigned int bc = s_cnt[0][b] + s_cnt[1][b] + s_cnt[2][b] + s_cnt[3][b];
            atomicAdd(&g_ss[b * SLOTS + slot], bs);
            atomicAdd(&g_cnt[b * SLOTS + slot], bc);
        }
    }
}

__global__ __launch_bounds__(64) void qrmse_final(
    const float* __restrict__ g_ss,
    const unsigned int* __restrict__ g_cnt,
    float* __restrict__ out)
{
    const int lane = threadIdx.x;  // 64 lanes, one per slot
    float ssb[NBINS];
    unsigned int cb[NBINS];
#pragma unroll
    for (int b = 0; b < NBINS; ++b) {
        ssb[b] = g_ss[b * SLOTS + lane];
        cb[b]  = g_cnt[b * SLOTS + lane];
    }
    for (int off = 32; off > 0; off >>= 1) {
#pragma unroll
        for (int b = 0; b < NBINS; ++b) {
            ssb[b] += __shfl_down(ssb[b], off);
            cb[b]  += __shfl_down(cb[b],  off);
        }
    }
    if (lane == 0) {
        float wsum = 0.f;
        float mse[NBINS], w[NBINS];
        bool any = false;
#pragma unroll
        for (int b = 0; b < NBINS; ++b) {
            bool present = (cb[b] > 0);
            any |= present;
            float csafe = present ? (float)cb[b] : 1.0f;
            mse[b] = ssb[b] / csafe;
            w[b] = present ? (1.0f / csafe) : 0.0f;
            wsum += w[b];
        }
        float denom = (wsum > 0.f) ? wsum : 1.0f;
        float wmse = 0.f;
#pragma unroll
        for (int b = 0; b < NBINS; ++b) wmse += (w[b] / denom) * mse[b];
        out[0] = any ? sqrtf(wmse + 1e-8f) : 0.0f;
    }
}

extern "C" void kernel_launch(void* const* d_in, const int* in_sizes, int n_in,
                              void* d_out, int out_size, void* d_ws, size_t ws_size,
                              hipStream_t stream) {
    const float* yp = (const float*)d_in[0];
    const float* yt = (const float*)d_in[1];
    float* out = (float*)d_out;

    float* g_ss = (float*)d_ws;                                   // 4*64 floats
    unsigned int* g_cnt = (unsigned int*)d_ws + NBINS * SLOTS;    // 4*64 uints

    int n = in_sizes[0];
    int n4 = n / 4;

    hipMemsetAsync(d_ws, 0, 2 * NBINS * SLOTS * sizeof(float), stream);

    const int block = 256;
    const int per_block = block * UNROLL;                 // 1024 float4s / block
    const int grid = (n4 + per_block - 1) / per_block;    // 8640 for this N
    qrmse_bins<<<grid, block, 0, stream>>>(
        (const float4*)yp, (const float4*)yt, yp, yt, g_ss, g_cnt, n4, n);
    qrmse_final<<<1, 64, 0, stream>>>(g_ss, g_cnt, out);
}